// Round 1
// 637.608 us; speedup vs baseline: 1.1195x; 1.1195x over previous
//
#include <hip/hip_runtime.h>
#include <hip/hip_fp16.h>
#include <cstdint>
#include <cstddef>

// ---------------------------------------------------------------------------
// GCNClassifier: 3x (GCNConv + tanh) + linear head, N=100k nodes, E=3.2M edges
// Round 10: layers 1+2 GEMM moved to MFMA (bf16 3-term split: XhiWhi + XhiWlo
// + XloWhi, rel err ~2^-17, far below existing fp16 Hs storage error).
//  - W pre-packed into fragment-ordered hi/lo bf16 by pack_w (aliased onto
//    histG scratch, dead after finalize_scan).
//  - K-permutation-safe: A and B frags use the SAME (group,reg)->k bijection,
//    so dot product is invariant to the HW's internal K layout. C/D layout is
//    the HW-verified col=lane&15, row=(lane>>4)*4+reg.
//  - gemm_mfma: 4 waves/block, 2 rowfrags x 8/4 colfrags per wave, zero LDS.
// Layer-3 gemm + all pull kernels unchanged from round 9.
// ---------------------------------------------------------------------------

#define EPB 16384        // edges per hist/scatter chunk
#define BSHIFT 8         // bucket = dst >> 8 (256 dst nodes per bucket)
#define NBUC_MAX 512     // 100000>>8 = 390 max bucket id
#define BCAP 12800       // bucket_build LDS edge capacity (avg 8192, 50+ sigma)

typedef __attribute__((ext_vector_type(8))) short short8;
typedef __attribute__((ext_vector_type(4))) float f32x4;

// --- generic two-level exclusive scan ---
__global__ __launch_bounds__(256) void scan_block(const int* __restrict__ src, int n,
                                                  int* __restrict__ incl,
                                                  int* __restrict__ bsum) {
    int tid = threadIdx.x;
    int v = blockIdx.x * 256 + tid;
    int val = (v < n) ? src[v] : 0;
    int lane = tid & 63, w = tid >> 6;
#pragma unroll
    for (int off = 1; off < 64; off <<= 1) {
        int t = __shfl_up(val, off, 64);
        if (lane >= off) val += t;
    }
    __shared__ int wsum[4];
    if (lane == 63) wsum[w] = val;
    __syncthreads();
#pragma unroll
    for (int i = 0; i < 4; ++i)
        if (i < w) val += wsum[i];
    if (v < n) incl[v] = val;
    if (tid == 255) bsum[blockIdx.x] = val;
}

__global__ __launch_bounds__(512) void scan_sums(int* __restrict__ bsum, int nb) {
    int tid = threadIdx.x;              // nb <= 512
    int val = (tid < nb) ? bsum[tid] : 0;
    int lane = tid & 63, w = tid >> 6;
#pragma unroll
    for (int off = 1; off < 64; off <<= 1) {
        int t = __shfl_up(val, off, 64);
        if (lane >= off) val += t;
    }
    __shared__ int wsum[8];
    if (lane == 63) wsum[w] = val;
    __syncthreads();
#pragma unroll
    for (int i = 0; i < 8; ++i)
        if (i < w) val += wsum[i];
    if (tid < nb) bsum[tid] = val;
}

__global__ __launch_bounds__(256) void finalize_scan(
    const int* __restrict__ incl, const int* __restrict__ bsum,
    const int* __restrict__ src, int n, int* __restrict__ excl) {
    int v = blockIdx.x * 256 + threadIdx.x;
    if (v >= n) return;
    int boff = (blockIdx.x == 0) ? 0 : bsum[blockIdx.x - 1];
    excl[v] = boff + incl[v] - src[v];
}

// Pass A: per-chunk histogram over dst buckets (LDS atomics only).
__global__ __launch_bounds__(256) void hist_bucket(
    const int* __restrict__ ei, int E, int nbuc, int nch,
    int* __restrict__ histG) {
    __shared__ int h[NBUC_MAX];
    const int k = blockIdx.x;
    for (int b = threadIdx.x; b < NBUC_MAX; b += 256) h[b] = 0;
    __syncthreads();
    const int base = k * EPB, end = min(E, base + EPB);
    for (int i = base + threadIdx.x; i < end; i += 256)
        atomicAdd(&h[ei[(size_t)E + i] >> BSHIFT], 1);
    __syncthreads();
    for (int b = threadIdx.x; b < nbuc; b += 256)
        histG[(size_t)b * nch + k] = h[b];
}

// Pass C: scatter (src,dst) pairs into per-(bucket,chunk) contiguous regions.
__global__ __launch_bounds__(256) void bucket_scatter(
    const int* __restrict__ ei, int E, int nbuc, int nch,
    const int* __restrict__ offs, uint2* __restrict__ ebuf) {
    __shared__ int cur[NBUC_MAX];
    const int k = blockIdx.x;
    for (int b = threadIdx.x; b < nbuc; b += 256)
        cur[b] = offs[(size_t)b * nch + k];
    __syncthreads();
    const int base = k * EPB, end = min(E, base + EPB);
    for (int i = base + threadIdx.x; i < end; i += 256) {
        int s = ei[i];
        int d = ei[(size_t)E + i];
        int pos = atomicAdd(&cur[d >> BSHIFT], 1);
        ebuf[pos] = make_uint2((unsigned)s, (unsigned)d);
    }
}

// Pass D: one block per bucket -> exact CSR slice + deg/row_start/dinv.
__global__ __launch_bounds__(256) void bucket_build(
    const uint2* __restrict__ ebuf, const int* __restrict__ offs,
    int E, int nbuc, int nch, int n,
    int* __restrict__ col, int* __restrict__ deg,
    int* __restrict__ row_start, float* __restrict__ dinv) {
    const int b = blockIdx.x;
    const int tid = threadIdx.x;
    const int estart = offs[(size_t)b * nch];
    const int eend = (b + 1 < nbuc) ? offs[(size_t)(b + 1) * nch] : E;
    const int cnt = eend - estart;

    __shared__ int degl[256];
    __shared__ int curl[256];
    __shared__ int wsum[4];
    __shared__ int colstage[BCAP];

    degl[tid] = 0;
    __syncthreads();
    for (int i = tid; i < cnt; i += 256)
        atomicAdd(&degl[ebuf[estart + i].y & 255], 1);
    __syncthreads();
    int myDeg = degl[tid];
    int val = myDeg;
    int lane = tid & 63, w = tid >> 6;
#pragma unroll
    for (int off = 1; off < 64; off <<= 1) {
        int t = __shfl_up(val, off, 64);
        if (lane >= off) val += t;
    }
    if (lane == 63) wsum[w] = val;
    __syncthreads();
#pragma unroll
    for (int i = 0; i < 4; ++i)
        if (i < w) val += wsum[i];
    int excl = val - myDeg;
    curl[tid] = excl;
    int v = (b << BSHIFT) + tid;
    if (v < n) {
        deg[v] = myDeg;
        row_start[v] = estart + excl;
        dinv[v] = rsqrtf((float)(myDeg + 1));   // +1 self loop
    }
    __syncthreads();
    if (cnt <= BCAP) {
        for (int i = tid; i < cnt; i += 256) {
            uint2 e = ebuf[estart + i];
            int pos = atomicAdd(&curl[e.y & 255], 1);
            colstage[pos] = (int)e.x;
        }
        __syncthreads();
        for (int i = tid; i < cnt; i += 256)
            col[estart + i] = colstage[i];
    } else {  // safety fallback
        for (int i = tid; i < cnt; i += 256) {
            uint2 e = ebuf[estart + i];
            int pos = atomicAdd(&curl[e.y & 255], 1);
            col[estart + pos] = (int)e.x;
        }
    }
}

__device__ inline unsigned int pack2h(float a, float b) {
    __half ha = __float2half_rn(a), hb = __float2half_rn(b);
    unsigned short ua = *(unsigned short*)&ha, ub = *(unsigned short*)&hb;
    return (unsigned int)ua | ((unsigned int)ub << 16);
}

// --- bf16 split helpers (round-to-nearest-even) ---
__device__ inline unsigned short f32_to_bf16_rn(float f) {
    unsigned int u = __float_as_uint(f);
    unsigned int r = (u + 0x7FFFu + ((u >> 16) & 1u)) >> 16;
    return (unsigned short)r;
}
__device__ inline float bf16_to_f32(unsigned short h) {
    return __uint_as_float(((unsigned int)h) << 16);
}

// Pre-pack W (FIN x FOUT, f32) into fragment-ordered hi/lo bf16.
// Slot layout: Wpk[((kc*CF+cf)*64 + lane)*16 + {0..7}=hi_j, {8..15}=lo_j]
// where frag value j of lane l covers W[kc*32 + (l>>4)*8 + j][cf*16 + (l&15)].
// This is the SAME (group,reg)->k bijection the A-frag loader uses, so the
// MFMA dot product is exact regardless of the HW's internal K ordering.
template <int FIN, int FOUT>
__global__ __launch_bounds__(256) void pack_w(const float* __restrict__ W,
                                              unsigned short* __restrict__ Wpk) {
    constexpr int KC = FIN / 32, CF = FOUT / 16;
    constexpr int TOT = KC * CF * 64 * 8;
    int idx = blockIdx.x * 256 + threadIdx.x;
    if (idx >= TOT) return;
    int j = idx & 7;
    int lane = (idx >> 3) & 63;
    int cf = (idx >> 9) % CF;
    int kc = (idx >> 9) / CF;
    int k = kc * 32 + ((lane >> 4) * 8) + j;
    int c = cf * 16 + (lane & 15);
    float w = W[(size_t)k * FOUT + c];
    unsigned short h = f32_to_bf16_rn(w);
    unsigned short l = f32_to_bf16_rn(w - bf16_to_f32(h));
    size_t base = ((size_t)((kc * CF + cf) * 64 + lane)) * 16;
    Wpk[base + j] = h;
    Wpk[base + 8 + j] = l;
}

// MFMA GEMM: Hs = fp16( (X @ W) * dinv[row] ), error-compensated bf16 split.
// acc += Xhi*Whi + Xhi*Wlo + Xlo*Whi  (XloWlo term ~2^-18 rel, dropped).
// 4 waves/block, each wave: 2 rowfrags (32 rows) x CF colfrags. No LDS:
// A straight from global (128B-per-row-per-chunk, cache-line exact), B from
// the pre-packed frag buffer (identical addresses across waves -> L1 hits).
template <int FIN, int FOUT>
__global__ __launch_bounds__(256) void gemm_mfma(
    const float* __restrict__ X, const unsigned short* __restrict__ Wpk,
    const float* __restrict__ dinv, __half* __restrict__ Hs, int n) {
    constexpr int KC = FIN / 32, CF = FOUT / 16, RF = 2;
    constexpr int BM = 4 * RF * 16;   // 128 rows per block
    const int w = threadIdx.x >> 6, lane = threadIdx.x & 63;
    const int g = lane >> 4, rr = lane & 15;
    const int node0 = blockIdx.x * BM + w * (RF * 16);
    const int ko = g * 8;

    f32x4 acc[RF][CF];
#pragma unroll
    for (int rf = 0; rf < RF; ++rf)
#pragma unroll
        for (int cf = 0; cf < CF; ++cf)
            acc[rf][cf] = (f32x4){0.f, 0.f, 0.f, 0.f};

    union U16 { uint4 u; short8 s; };

    for (int kc = 0; kc < KC; ++kc) {
        short8 ahi[RF], alo[RF];
#pragma unroll
        for (int rf = 0; rf < RF; ++rf) {
            int r = node0 + rf * 16 + rr;
            float xv[8] = {0.f, 0.f, 0.f, 0.f, 0.f, 0.f, 0.f, 0.f};
            if (r < n) {
                const float* xp = X + (size_t)r * FIN + kc * 32 + ko;
                float4 a0 = *(const float4*)xp;
                float4 a1 = *(const float4*)(xp + 4);
                xv[0] = a0.x; xv[1] = a0.y; xv[2] = a0.z; xv[3] = a0.w;
                xv[4] = a1.x; xv[5] = a1.y; xv[6] = a1.z; xv[7] = a1.w;
            }
#pragma unroll
            for (int j = 0; j < 8; ++j) {
                unsigned short hb = f32_to_bf16_rn(xv[j]);
                float rem = xv[j] - bf16_to_f32(hb);
                ahi[rf][j] = (short)hb;
                alo[rf][j] = (short)f32_to_bf16_rn(rem);
            }
        }
#pragma unroll
        for (int cf = 0; cf < CF; ++cf) {
            const uint4* bp = (const uint4*)(Wpk +
                ((size_t)((kc * CF + cf) * 64 + lane)) * 16);
            U16 bh, bl;
            bh.u = bp[0];
            bl.u = bp[1];
#pragma unroll
            for (int rf = 0; rf < RF; ++rf) {
                acc[rf][cf] = __builtin_amdgcn_mfma_f32_16x16x32_bf16(
                    ahi[rf], bh.s, acc[rf][cf], 0, 0, 0);
                acc[rf][cf] = __builtin_amdgcn_mfma_f32_16x16x32_bf16(
                    alo[rf], bh.s, acc[rf][cf], 0, 0, 0);
                acc[rf][cf] = __builtin_amdgcn_mfma_f32_16x16x32_bf16(
                    ahi[rf], bl.s, acc[rf][cf], 0, 0, 0);
            }
        }
    }

    // D layout (HW-verified): col = lane&15, row = (lane>>4)*4 + reg.
#pragma unroll
    for (int rf = 0; rf < RF; ++rf) {
#pragma unroll
        for (int i = 0; i < 4; ++i) {
            int r = node0 + rf * 16 + g * 4 + i;
            if (r >= n) continue;
            float di = dinv[r];
            __half* hp = Hs + (size_t)r * FOUT + rr;
#pragma unroll
            for (int cf = 0; cf < CF; ++cf)
                hp[cf * 16] = __float2half_rn(acc[rf][cf][i] * di);
        }
    }
}

// Register-tiled f32 GEMM (kept for layer 3: 64 -> 16).
template <int FIN, int FOUT, int TM>
__global__ __launch_bounds__(256) void gemm_tile_h(
    const float* __restrict__ X, const float* __restrict__ W,
    const float* __restrict__ dinv, __half* __restrict__ Hs, int n) {
    constexpr int CT = FOUT / 4;
    constexpr int RG = 256 / CT;
    static_assert(TM == RG * 4, "tile mismatch");
    constexpr int LROW = FIN + 4;   // rows stay 16-B aligned (FIN,4 mult of 4)
    __shared__ float xs[TM][LROW];

    const int node0 = blockIdx.x * TM;
    const int tid = threadIdx.x;

    constexpr int C4 = FIN / 4;
    for (int i = tid; i < TM * C4; i += 256) {
        int r = i / C4, c = i % C4;
        float4 v = make_float4(0.f, 0.f, 0.f, 0.f);
        if (node0 + r < n) v = *(const float4*)(X + (size_t)(node0 + r) * FIN + c * 4);
        *(float4*)&xs[r][c * 4] = v;
    }
    __syncthreads();

    const int col = (tid % CT) * 4;
    const int r0 = (tid / CT) * 4;

    float acc[4][4];
#pragma unroll
    for (int i = 0; i < 4; ++i)
#pragma unroll
        for (int j = 0; j < 4; ++j) acc[i][j] = 0.f;

#pragma unroll 2
    for (int k = 0; k < FIN; k += 4) {
        float4 w0 = *(const float4*)(W + (size_t)(k + 0) * FOUT + col);
        float4 w1 = *(const float4*)(W + (size_t)(k + 1) * FOUT + col);
        float4 w2 = *(const float4*)(W + (size_t)(k + 2) * FOUT + col);
        float4 w3 = *(const float4*)(W + (size_t)(k + 3) * FOUT + col);
        float4 av[4];
        av[0] = *(const float4*)&xs[r0 + 0][k];
        av[1] = *(const float4*)&xs[r0 + 1][k];
        av[2] = *(const float4*)&xs[r0 + 2][k];
        av[3] = *(const float4*)&xs[r0 + 3][k];
#pragma unroll
        for (int rr = 0; rr < 4; ++rr) {
            acc[rr][0] = fmaf(av[rr].x, w0.x, acc[rr][0]);
            acc[rr][1] = fmaf(av[rr].x, w0.y, acc[rr][1]);
            acc[rr][2] = fmaf(av[rr].x, w0.z, acc[rr][2]);
            acc[rr][3] = fmaf(av[rr].x, w0.w, acc[rr][3]);
            acc[rr][0] = fmaf(av[rr].y, w1.x, acc[rr][0]);
            acc[rr][1] = fmaf(av[rr].y, w1.y, acc[rr][1]);
            acc[rr][2] = fmaf(av[rr].y, w1.z, acc[rr][2]);
            acc[rr][3] = fmaf(av[rr].y, w1.w, acc[rr][3]);
            acc[rr][0] = fmaf(av[rr].z, w2.x, acc[rr][0]);
            acc[rr][1] = fmaf(av[rr].z, w2.y, acc[rr][1]);
            acc[rr][2] = fmaf(av[rr].z, w2.z, acc[rr][2]);
            acc[rr][3] = fmaf(av[rr].z, w2.w, acc[rr][3]);
            acc[rr][0] = fmaf(av[rr].w, w3.x, acc[rr][0]);
            acc[rr][1] = fmaf(av[rr].w, w3.y, acc[rr][1]);
            acc[rr][2] = fmaf(av[rr].w, w3.z, acc[rr][2]);
            acc[rr][3] = fmaf(av[rr].w, w3.w, acc[rr][3]);
        }
    }

#pragma unroll
    for (int rr = 0; rr < 4; ++rr) {
        int node = node0 + r0 + rr;
        if (node < n) {
            float di = dinv[node];
            uint2 pk;
            pk.x = pack2h(acc[rr][0] * di, acc[rr][1] * di);
            pk.y = pack2h(acc[rr][2] * di, acc[rr][3] * di);
            *(uint2*)(Hs + (size_t)node * FOUT + col) = pk;
        }
    }
}

__device__ inline void add8h(float* acc, uint4 p) {
    unsigned int w[4] = {p.x, p.y, p.z, p.w};
#pragma unroll
    for (int t = 0; t < 4; ++t) {
        __half2 h = *(const __half2*)&w[t];
        float2 f = __half22float2(h);
        acc[2 * t] += f.x;
        acc[2 * t + 1] += f.y;
    }
}

// Pull aggregation + norm + bias + tanh from fp16 Hs. F/8 lanes per dst node,
// 8 neighbor rows in flight per lane (MLP depth 8).
template <int F>
__global__ __launch_bounds__(256) void pull_agg_h(
    const int* __restrict__ row_start, const int* __restrict__ deg,
    const int* __restrict__ col, const __half* __restrict__ Hs,
    const float* __restrict__ dinv, const float* __restrict__ B,
    float* __restrict__ OUT, int n) {
    constexpr int TPE = F / 8;
    long long gid = (long long)blockIdx.x * 256 + threadIdx.x;
    int node = (int)(gid / TPE);
    int lane = (int)(gid % TPE);
    if (node >= n) return;
    const int beg = row_start[node];
    const int cnt = deg[node];
    const size_t lo = (size_t)lane * 8;

    float acc[8] = {0.f, 0.f, 0.f, 0.f, 0.f, 0.f, 0.f, 0.f};
    add8h(acc, *(const uint4*)(Hs + (size_t)node * F + lo));  // self term

    int j = 0;
    for (; j + 8 <= cnt; j += 8) {
        int s0 = col[beg + j + 0], s1 = col[beg + j + 1];
        int s2 = col[beg + j + 2], s3 = col[beg + j + 3];
        int s4 = col[beg + j + 4], s5 = col[beg + j + 5];
        int s6 = col[beg + j + 6], s7 = col[beg + j + 7];
        uint4 p0 = *(const uint4*)(Hs + (size_t)s0 * F + lo);
        uint4 p1 = *(const uint4*)(Hs + (size_t)s1 * F + lo);
        uint4 p2 = *(const uint4*)(Hs + (size_t)s2 * F + lo);
        uint4 p3 = *(const uint4*)(Hs + (size_t)s3 * F + lo);
        uint4 p4 = *(const uint4*)(Hs + (size_t)s4 * F + lo);
        uint4 p5 = *(const uint4*)(Hs + (size_t)s5 * F + lo);
        uint4 p6 = *(const uint4*)(Hs + (size_t)s6 * F + lo);
        uint4 p7 = *(const uint4*)(Hs + (size_t)s7 * F + lo);
        add8h(acc, p0); add8h(acc, p1); add8h(acc, p2); add8h(acc, p3);
        add8h(acc, p4); add8h(acc, p5); add8h(acc, p6); add8h(acc, p7);
    }
    for (; j < cnt; ++j) {
        int s = col[beg + j];
        add8h(acc, *(const uint4*)(Hs + (size_t)s * F + lo));
    }

    float di = dinv[node];
    float4 b0 = *(const float4*)(B + lo);
    float4 b1 = *(const float4*)(B + lo + 4);
    float4 r0, r1;
    r0.x = tanhf(fmaf(acc[0], di, b0.x));
    r0.y = tanhf(fmaf(acc[1], di, b0.y));
    r0.z = tanhf(fmaf(acc[2], di, b0.z));
    r0.w = tanhf(fmaf(acc[3], di, b0.w));
    r1.x = tanhf(fmaf(acc[4], di, b1.x));
    r1.y = tanhf(fmaf(acc[5], di, b1.y));
    r1.z = tanhf(fmaf(acc[6], di, b1.z));
    r1.w = tanhf(fmaf(acc[7], di, b1.w));
    float* op = OUT + (size_t)node * F + lo;
    *(float4*)(op) = r0;
    *(float4*)(op + 4) = r1;
}

__global__ void classifier_kernel(const float* __restrict__ Hf,
                                  const float* __restrict__ Wc,
                                  const float* __restrict__ bc,
                                  float* __restrict__ out, int n) {
    int v = blockIdx.x * blockDim.x + threadIdx.x;
    if (v >= n) return;
    float o0 = bc[0], o1 = bc[1];
    const float* h = Hf + (size_t)v * 16;
#pragma unroll
    for (int k = 0; k < 16; ++k) {
        float hv = h[k];
        o0 = fmaf(hv, Wc[k * 2 + 0], o0);
        o1 = fmaf(hv, Wc[k * 2 + 1], o1);
    }
    out[(size_t)v * 2 + 0] = o0;
    out[(size_t)v * 2 + 1] = o1;
}

extern "C" void kernel_launch(void* const* d_in, const int* in_sizes, int n_in,
                              void* d_out, int out_size, void* d_ws, size_t ws_size,
                              hipStream_t stream) {
    const float* x  = (const float*)d_in[0];
    const int* ei   = (const int*)d_in[1];   // int32 (harness converts)
    const float* W1 = (const float*)d_in[2];
    const float* b1 = (const float*)d_in[3];
    const float* W2 = (const float*)d_in[4];
    const float* b2 = (const float*)d_in[5];
    const float* W3 = (const float*)d_in[6];
    const float* b3 = (const float*)d_in[7];
    const float* Wc = (const float*)d_in[8];
    const float* bc = (const float*)d_in[9];

    const int n = in_sizes[0] / 256;
    const int E = in_sizes[1] / 2;
    const int nbuc = (n + 255) >> BSHIFT;          // 391
    const int nch  = (E + EPB - 1) / EPB;          // 196
    const int NH   = nbuc * nch;                   // 76,636
    const int nb2  = (NH + 255) / 256;             // 300 <= 512

    float* outp = (float*)d_out;             // [n,2]
    float* outh = outp + (size_t)n * 2;      // [n,16]

    int*    deg       = (int*)d_ws;
    float*  dinv      = (float*)d_ws + (size_t)n;
    int*    row_start = (int*)d_ws + 2 * (size_t)n;
    int*    histG     = (int*)d_ws + 3 * (size_t)n;
    int*    incl      = histG + NH;
    int*    bsum      = incl + NH;
    int*    offs      = bsum + 512;
    int*    col       = offs + NH;
    __half* HsH       = (__half*)(col + E);
    float*  xbuf      = (float*)(HsH + (size_t)n * 128);
    uint2*  ebuf      = (uint2*)xbuf;        // alias: dead before pull1 writes xbuf

    // Packed-W buffers alias histG (NH*4 = 306 KB; dead after finalize_scan).
    // Wpk1: 256*128*4 B = 128 KB; Wpk2: 128*64*4 B = 32 KB. 160 KB < 306 KB.
    unsigned short* Wpk1 = (unsigned short*)histG;
    unsigned short* Wpk2 = Wpk1 + (size_t)256 * 128 * 2;

    // --- atomic-free CSR build (shared by all 3 layers) ---
    hist_bucket<<<nch, 256, 0, stream>>>(ei, E, nbuc, nch, histG);
    scan_block<<<nb2, 256, 0, stream>>>(histG, NH, incl, bsum);
    scan_sums<<<1, 512, 0, stream>>>(bsum, nb2);
    finalize_scan<<<nb2, 256, 0, stream>>>(incl, bsum, histG, NH, offs);
    bucket_scatter<<<nch, 256, 0, stream>>>(ei, E, nbuc, nch, offs, ebuf);
    bucket_build<<<nbuc, 256, 0, stream>>>(ebuf, offs, E, nbuc, nch, n,
                                           col, deg, row_start, dinv);

    // --- pack W1/W2 into MFMA fragment order (histG dead by now) ---
    pack_w<256, 128><<<(256 / 32 * 128 / 16 * 512 + 255) / 256, 256, 0, stream>>>(W1, Wpk1);
    pack_w<128, 64><<<(128 / 32 * 64 / 16 * 512 + 255) / 256, 256, 0, stream>>>(W2, Wpk2);

    // --- layer 1: 256 -> 128 (MFMA) ---
    gemm_mfma<256, 128><<<(n + 127) / 128, 256, 0, stream>>>(x, Wpk1, dinv, HsH, n);
    pull_agg_h<128><<<(int)(((long long)n * 16 + 255) / 256), 256, 0, stream>>>(
        row_start, deg, col, HsH, dinv, b1, xbuf, n);

    // --- layer 2: 128 -> 64 (MFMA) ---
    gemm_mfma<128, 64><<<(n + 127) / 128, 256, 0, stream>>>(xbuf, Wpk2, dinv, HsH, n);
    pull_agg_h<64><<<(int)(((long long)n * 8 + 255) / 256), 256, 0, stream>>>(
        row_start, deg, col, HsH, dinv, b2, xbuf, n);

    // --- layer 3: 64 -> 16 (f32 path, already small) ---
    gemm_tile_h<64, 16, 256><<<(n + 255) / 256, 256, 0, stream>>>(xbuf, W3, dinv, HsH, n);
    pull_agg_h<16><<<(int)(((long long)n * 2 + 255) / 256), 256, 0, stream>>>(
        row_start, deg, col, HsH, dinv, b3, outh, n);

    // --- classifier head ---
    classifier_kernel<<<(n + 255) / 256, 256, 0, stream>>>(outh, Wc, bc, outp, n);
}